// Round 6
// baseline (19958.150 us; speedup 1.0000x reference)
//
#include <hip/hip_runtime.h>
#include <math.h>

// Problem constants
#define NB   32      // batch
#define NT   300     // encoder frames
#define NE   1024    // encoder dim
#define NH   512     // hidden
#define NA   256     // attention dim
#define NC   10      // conv channels
#define NKW  201     // conv kernel width (2K+1), K=100
#define NV   10000   // vocab
#define NEMB 512     // embedding dim
#define NAO  512     // attention output dim
#define NTD  80      // decode steps
#define SCL  2.0f
#define NLOGB 1252   // k_logits total blocks (313*4)
#define NELECT 32    // elected fin blocks

__device__ __forceinline__ float sigf(float x){ return 1.f/(1.f+expf(-x)); }

// ---------------------------------------------------------------------------
// init: zbuf=0, dec_c(A)=0, cvp(5 parts)=0, wbuf=w0, prev=BOS, abar/lbar=0
// ---------------------------------------------------------------------------
__global__ __launch_bounds__(256) void k_init(const int* __restrict__ enc_len,
    float* __restrict__ zbuf, float* __restrict__ cA, float* __restrict__ cvp,
    float* __restrict__ wbuf, int* __restrict__ prev, int* __restrict__ abar,
    int* __restrict__ lbar)
{
    int i = blockIdx.x*256 + threadIdx.x;           // 131072 threads
    if (i < NB*NH)    { zbuf[i]=0.f; cA[i]=0.f; }
    if (i < 5*NB*NAO)   cvp[i]=0.f;
    if (i < NB*NT)    { int b=i/NT, t=i%NT; int len=enc_len[b];
                        wbuf[i] = (t<len)? 1.f/(float)len : 0.f; }
    if (i < NB)         prev[i]=1;                  // BOS
    if (i < NTD*NB)     abar[i]=0;
    if (i < NTD)        lbar[i]=0;
}

// ---------------------------------------------------------------------------
// Tiled GEMM: Cg[m][n] = A[m][:1024] . Wg[n][:1024] + bias[n].
// M=9600 rows, K=1024 exact.  Used for pre_enc (N=256) and ENC_O (N=512).
// ---------------------------------------------------------------------------
__global__ __launch_bounds__(256) void k_gemm_pre(const float* __restrict__ Ag,
    const float* __restrict__ Wg, const float* __restrict__ bias,
    float* __restrict__ Cg, int N)
{
    __shared__ float As[32][68];   // [kk][m]
    __shared__ float Bs[32][68];   // [kk][n]
    const int tid = threadIdx.x;
    const int m0 = blockIdx.y*64, n0 = blockIdx.x*64;
    const int r  = tid>>2, kg = (tid&3)*8;
    const int ty = tid>>4, tx = tid&15;
    float acc[4][4] = {};
    for (int k0 = 0; k0 < 1024; k0 += 32) {
        const float4 a0 = *(const float4*)(Ag + (size_t)(m0+r)*1024 + k0+kg);
        const float4 a1 = *(const float4*)(Ag + (size_t)(m0+r)*1024 + k0+kg+4);
        const float4 b0 = *(const float4*)(Wg + (size_t)(n0+r)*1024 + k0+kg);
        const float4 b1 = *(const float4*)(Wg + (size_t)(n0+r)*1024 + k0+kg+4);
        __syncthreads();
        As[kg+0][r]=a0.x; As[kg+1][r]=a0.y; As[kg+2][r]=a0.z; As[kg+3][r]=a0.w;
        As[kg+4][r]=a1.x; As[kg+5][r]=a1.y; As[kg+6][r]=a1.z; As[kg+7][r]=a1.w;
        Bs[kg+0][r]=b0.x; Bs[kg+1][r]=b0.y; Bs[kg+2][r]=b0.z; Bs[kg+3][r]=b0.w;
        Bs[kg+4][r]=b1.x; Bs[kg+5][r]=b1.y; Bs[kg+6][r]=b1.z; Bs[kg+7][r]=b1.w;
        __syncthreads();
        #pragma unroll
        for (int kk=0; kk<32; ++kk) {
            const float4 av = *(const float4*)&As[kk][ty*4];
            const float4 bv = *(const float4*)&Bs[kk][tx*4];
            const float a[4]={av.x,av.y,av.z,av.w};
            const float bb[4]={bv.x,bv.y,bv.z,bv.w};
            #pragma unroll
            for (int i=0;i<4;++i)
                #pragma unroll
                for (int j=0;j<4;++j) acc[i][j] += a[i]*bb[j];
        }
    }
    #pragma unroll
    for (int i=0;i<4;++i){
        const int m = m0 + ty*4 + i;
        #pragma unroll
        for (int j=0;j<4;++j)
            Cg[(size_t)m*N + n0 + tx*4 + j] = acc[i][j] + bias[n0+tx*4+j];
    }
}

// ---------------------------------------------------------------------------
// gates partials: gp[kp][b][n] = sum_{k chunk} x[b][k]*Wcat[n][k]
// x = [emb[prev] | cvec=sum cvp0..4 | dec_z], grid (64,4), 256 thr.
// ---------------------------------------------------------------------------
__global__ __launch_bounds__(256) void k_gates(const float* __restrict__ emb,
    const int* __restrict__ prev, const float* __restrict__ cp,
    const float* __restrict__ zbuf, const float* __restrict__ W_ih,
    const float* __restrict__ W_hh, float* __restrict__ gp)
{
    __shared__ float xt[32][68];
    const int tid = threadIdx.x;
    const int kp  = blockIdx.y;                    // 0..3, chunks of 384
    const int lane = tid&63, wv = tid>>6;
    const int bs = lane&15, nsl = lane>>4;
    const int n0 = blockIdx.x*32 + wv*8 + nsl*2;
    const int sb = tid>>3, sk = (tid&7)*8;
    const int pvs = prev[sb];
    const float* wih0 = W_ih + (size_t)n0*1024;
    const float* whh0 = W_hh + (size_t)n0*512;
    float a00=0.f,a01=0.f,a10=0.f,a11=0.f;
    for (int tile=0; tile<6; ++tile) {
        const int k0 = kp*384 + tile*64;
        const int gk = k0 + sk;
        float4 v0, v1;
        if (gk < 512) {
            const float4* p = (const float4*)(emb + (size_t)pvs*NEMB + gk);
            v0 = p[0]; v1 = p[1];
        } else if (gk < 1024) {
            const int off = gk-512;
            float4 s0 = make_float4(0.f,0.f,0.f,0.f);
            float4 s1 = make_float4(0.f,0.f,0.f,0.f);
            #pragma unroll
            for (int j=0;j<5;++j){
                const float4* p = (const float4*)(cp + (size_t)j*NB*NAO + sb*NAO + off);
                const float4 u0=p[0], u1=p[1];
                s0.x+=u0.x; s0.y+=u0.y; s0.z+=u0.z; s0.w+=u0.w;
                s1.x+=u1.x; s1.y+=u1.y; s1.z+=u1.z; s1.w+=u1.w;
            }
            v0 = s0; v1 = s1;
        } else {
            const float4* p = (const float4*)(zbuf + sb*NH + (gk-1024));
            v0 = p[0]; v1 = p[1];
        }
        __syncthreads();
        *(float4*)&xt[sb][sk]   = v0;
        *(float4*)&xt[sb][sk+4] = v1;
        __syncthreads();
        const float* w0 = (k0 < 1024) ? wih0 + k0        : whh0 + (k0-1024);
        const float* w1 = (k0 < 1024) ? wih0 + 1024 + k0 : whh0 + 512 + (k0-1024);
        #pragma unroll
        for (int c=0;c<16;++c){
            const float4 xa = *(const float4*)&xt[bs][c*4];
            const float4 xb = *(const float4*)&xt[bs+16][c*4];
            const float4 wa = *(const float4*)(w0 + c*4);
            const float4 wb = *(const float4*)(w1 + c*4);
            a00 += xa.x*wa.x+xa.y*wa.y+xa.z*wa.z+xa.w*wa.w;
            a01 += xa.x*wb.x+xa.y*wb.y+xa.z*wb.z+xa.w*wb.w;
            a10 += xb.x*wa.x+xb.y*wa.y+xb.z*wa.z+xb.w*wa.w;
            a11 += xb.x*wb.x+xb.y*wb.y+xb.z*wb.z+xb.w*wb.w;
        }
    }
    float* g = gp + (size_t)(kp*NB)*2048;
    g[(size_t)bs*2048 + n0]        = a00;
    g[(size_t)bs*2048 + n0+1]      = a01;
    g[(size_t)(bs+16)*2048 + n0]   = a10;
    g[(size_t)(bs+16)*2048 + n0+1] = a11;
}

// ---------------------------------------------------------------------------
// FUSED lstm + dec_t + conv + escore + softmax + cvec-partial.
// grid (5 t-chunks, 32 b) = 160 blocks <= 256 CUs -> all blocks resident from
// dispatch, so the per-batch 5-block spin-join on abar is deadlock-free.
// After its 60-t escore slice each block joins its batch group, redundantly
// computes softmax (x5), and emits cvp[x][b][:512] for its 60-t chunk.
// Chunk-0 block writes dec_c/zbuf/wout/out_ws.
// ---------------------------------------------------------------------------
__global__ __launch_bounds__(256) void k_attn(
    const float* __restrict__ gp, const float* __restrict__ b_ih,
    const float* __restrict__ b_hh, const float* __restrict__ cin,
    float* __restrict__ cout, float* __restrict__ zbuf,
    const float* __restrict__ W_dec, const float* __restrict__ pre_enc,
    const float* __restrict__ win, const float* __restrict__ ck,
    const float* __restrict__ W_att, const float* __restrict__ W_g,
    float* __restrict__ ebuf, const float* __restrict__ enc_o,
    float* __restrict__ cvp, float* __restrict__ wout,
    float* __restrict__ out_ws, int* __restrict__ abar, int step)
{
    __shared__ float zs[NH];           // 512
    __shared__ float w_h[260];
    __shared__ float ck_s[NC*NKW];     // 2010
    __shared__ float wt_s[NA*NC];      // 2560
    __shared__ float dt_s[NA];
    __shared__ float wg_s[NA];
    __shared__ float cv_s[60*NC];      // 600
    __shared__ float ep_s[60][4];
    __shared__ float es[NT];
    __shared__ float wsm[NT];
    __shared__ float red[256];
    const int tid = threadIdx.x;
    const int b = blockIdx.y, x = blockIdx.x, t0 = x*60;
    // ---- LSTM combine (redundant per chunk; chunk 0 writes globals)
    for (int h = tid; h < NH; h += 256) {
        float g[4];
        #pragma unroll
        for (int r=0;r<4;++r){
            float s = b_ih[r*512+h] + b_hh[r*512+h];
            #pragma unroll
            for (int kp=0;kp<4;++kp) s += gp[(size_t)(kp*NB+b)*2048 + r*512 + h];
            g[r]=s;
        }
        const float c = sigf(g[1])*cin[b*NH+h] + sigf(g[0])*tanhf(g[2]);
        const float z = sigf(g[3])*tanhf(c);
        zs[h] = z;
        if (x==0){ cout[b*NH+h]=c; zbuf[b*NH+h]=z; }
    }
    // ---- constant/halo loads (independent of zs)
    for (int i=tid;i<260;i+=256){ const int gt=t0-100+i;
        w_h[i] = (gt>=0 && gt<NT)? win[b*NT+gt] : 0.f; }
    for (int i=tid;i<NC*NKW;i+=256) ck_s[i]=ck[i];
    for (int i=tid;i<NA*NC;i+=256)  wt_s[i]=W_att[i];
    wg_s[tid] = W_g[tid];
    __syncthreads();
    // ---- dec_t: 32 groups of 8 lanes; group handles a = grp*8..+7
    {
        const int grp = tid>>3, l = tid&7;
        float4 zr[16];
        #pragma unroll
        for (int q=0;q<16;++q) zr[q] = *(const float4*)&zs[l*4 + q*32];
        #pragma unroll
        for (int j=0;j<8;++j){
            const int a = grp*8 + j;
            const float* w = W_dec + (size_t)a*NH;
            float sv = 0.f;
            #pragma unroll
            for (int q=0;q<16;++q){
                const float4 wv4 = *(const float4*)(w + l*4 + q*32);
                sv += zr[q].x*wv4.x + zr[q].y*wv4.y + zr[q].z*wv4.z + zr[q].w*wv4.w;
            }
            sv += __shfl_down(sv, 4, 8);
            sv += __shfl_down(sv, 2, 8);
            sv += __shfl_down(sv, 1, 8);
            if (l==0) dt_s[a] = sv;
        }
    }
    __syncthreads();
    // ---- conv for this 60-t chunk
    for (int i=tid;i<60*NC;i+=256){
        const int tl=i/NC, ch=i%NC;
        float s=0.f;
        const float* wp  = &w_h[tl];
        const float* ckp = &ck_s[ch*NKW];
        for (int k=0;k<NKW;++k) s += wp[k]*ckp[k];
        cv_s[i]=s;
    }
    __syncthreads();
    // ---- escore
    const int tq = tid&3, tl = tid>>2;
    if (tl < 60) {
        float cv[NC];
        #pragma unroll
        for (int ch=0;ch<NC;++ch) cv[ch]=cv_s[tl*NC+ch];
        const float* pe = pre_enc + (size_t)(b*NT + t0 + tl)*NA;
        float part=0.f;
        for (int i=0;i<64;++i){
            const int aa = tq + 4*i;
            float attc = 0.f;
            #pragma unroll
            for (int ch=0;ch<NC;++ch) attc += cv[ch]*wt_s[aa*NC+ch];
            part += tanhf(pe[aa] + dt_s[aa] + attc) * wg_s[aa];
        }
        ep_s[tl][tq] = part;
    }
    __syncthreads();
    if (tid < 60)
        ebuf[b*NT + t0 + tid] = ep_s[tid][0]+ep_s[tid][1]+ep_s[tid][2]+ep_s[tid][3];
    // ---- join the 5 blocks of this batch (all resident: 160 blocks <= 256 CU)
    __syncthreads();
    if (tid==0){
        __threadfence();
        __hip_atomic_fetch_add(&abar[step*NB+b], 1, __ATOMIC_ACQ_REL,
                               __HIP_MEMORY_SCOPE_AGENT);
        while (__hip_atomic_load(&abar[step*NB+b], __ATOMIC_ACQUIRE,
                                 __HIP_MEMORY_SCOPE_AGENT) < 5) {}
    }
    __syncthreads();
    __threadfence();
    // ---- softmax over full ebuf[b] (redundant x5)
    for (int t=tid;t<NT;t+=256) es[t]=ebuf[b*NT+t];
    __syncthreads();
    float m=-3.4e38f;
    for (int t=tid;t<NT;t+=256) m=fmaxf(m,es[t]);
    red[tid]=m; __syncthreads();
    for (int r=128;r>0;r>>=1){ if(tid<r) red[tid]=fmaxf(red[tid],red[tid+r]); __syncthreads(); }
    m=red[0]; __syncthreads();
    float ss=0.f;
    for (int t=tid;t<NT;t+=256) ss+=expf(SCL*(es[t]-m));
    red[tid]=ss; __syncthreads();
    for (int r=128;r>0;r>>=1){ if(tid<r) red[tid]+=red[tid+r]; __syncthreads(); }
    const float inv = 1.f/red[0];
    for (int t=tid;t<NT;t+=256){
        const float w = expf(SCL*(es[t]-m))*inv;
        wsm[t]=w;
        if (x==0){ wout[b*NT+t]=w; out_ws[((size_t)b*NTD+step)*NT+t]=w; }
    }
    __syncthreads();
    // ---- cvec partial for this 60-t chunk: o = tid and tid+256
    const float* ep2 = enc_o + ((size_t)b*NT + t0)*NAO;
    float acc0=0.f, acc1=0.f;
    #pragma unroll 4
    for (int t=0;t<60;++t){
        const float w = wsm[t0+t];
        acc0 += w*ep2[(size_t)t*NAO + tid];
        acc1 += w*ep2[(size_t)t*NAO + tid + 256];
    }
    cvp[(size_t)(x*NB+b)*NAO + tid]       = acc0;
    cvp[(size_t)(x*NB+b)*NAO + tid + 256] = acc1;
}

// ---------------------------------------------------------------------------
// FUSED logits partials + finalize.  grid (313,4) = 1252 blocks.
// lp[kp][b][v] = sum_{k in 256-chunk} y[b][k]*W_out[v][k],
// y = [dec_z | cvec = cvp0+..+cvp4].  After writing lp each block does
// fence + fetch_add(lbar[step]); the LAST 32 blocks to arrive (r>=1220) spin
// until all 1252 increments land (they only wait on blocks already past
// their writes -> deadlock-free), then perform fin for batch b=r-1220.
// ---------------------------------------------------------------------------
__global__ __launch_bounds__(256) void k_logits(const float* __restrict__ zbuf,
    const float* __restrict__ cp, const float* __restrict__ W_out,
    float* __restrict__ lp, const float* __restrict__ b_out, int step,
    float* __restrict__ out_logits, int* __restrict__ prev,
    float* __restrict__ out_preds, float* __restrict__ out_ylp,
    int* __restrict__ lbar)
{
    __shared__ float xt[32][68];
    __shared__ float rv[256];
    __shared__ int   ri[256];
    __shared__ int   relect;
    const int tid=threadIdx.x, kp=blockIdx.y;
    const int lane=tid&63, wv=tid>>6, bs=lane&15, nsl=lane>>4;
    const int n0 = blockIdx.x*32 + wv*8 + nsl*2;
    const int rn0 = (n0   < NV)? n0   : NV-1;
    const int rn1 = (n0+1 < NV)? n0+1 : NV-1;
    const float* w0 = W_out + (size_t)rn0*1024;
    const float* w1 = W_out + (size_t)rn1*1024;
    const int sb = tid>>3, sk = (tid&7)*8;
    float a00=0.f,a01=0.f,a10=0.f,a11=0.f;
    for (int tile=0; tile<4; ++tile) {
        const int k0 = kp*256 + tile*64;
        const int gk = k0 + sk;
        float4 v0, v1;
        if (gk < 512) {
            const float4* p = (const float4*)(zbuf + sb*NH + gk);
            v0 = p[0]; v1 = p[1];
        } else {
            const int off = gk-512;
            float4 s0 = make_float4(0.f,0.f,0.f,0.f);
            float4 s1 = make_float4(0.f,0.f,0.f,0.f);
            #pragma unroll
            for (int j=0;j<5;++j){
                const float4* p = (const float4*)(cp + (size_t)j*NB*NAO + sb*NAO + off);
                const float4 u0=p[0], u1=p[1];
                s0.x+=u0.x; s0.y+=u0.y; s0.z+=u0.z; s0.w+=u0.w;
                s1.x+=u1.x; s1.y+=u1.y; s1.z+=u1.z; s1.w+=u1.w;
            }
            v0 = s0; v1 = s1;
        }
        __syncthreads();
        *(float4*)&xt[sb][sk]   = v0;
        *(float4*)&xt[sb][sk+4] = v1;
        __syncthreads();
        #pragma unroll
        for (int c=0;c<16;++c){
            const float4 xa = *(const float4*)&xt[bs][c*4];
            const float4 xb = *(const float4*)&xt[bs+16][c*4];
            const float4 wa = *(const float4*)(w0 + k0 + c*4);
            const float4 wb = *(const float4*)(w1 + k0 + c*4);
            a00 += xa.x*wa.x+xa.y*wa.y+xa.z*wa.z+xa.w*wa.w;
            a01 += xa.x*wb.x+xa.y*wb.y+xa.z*wb.z+xa.w*wb.w;
            a10 += xb.x*wa.x+xb.y*wa.y+xb.z*wa.z+xb.w*wa.w;
            a11 += xb.x*wb.x+xb.y*wb.y+xb.z*wb.z+xb.w*wb.w;
        }
    }
    if (n0 < NV){
        lp[(size_t)(kp*NB+bs)*NV + n0]    = a00;
        lp[(size_t)(kp*NB+bs+16)*NV + n0] = a10;
    }
    if (n0+1 < NV){
        lp[(size_t)(kp*NB+bs)*NV + n0+1]    = a01;
        lp[(size_t)(kp*NB+bs+16)*NV + n0+1] = a11;
    }
    // ---- election: last 32 blocks perform the finalize
    __syncthreads();
    if (tid==0){
        __threadfence();
        int r = __hip_atomic_fetch_add(&lbar[step], 1, __ATOMIC_ACQ_REL,
                                       __HIP_MEMORY_SCOPE_AGENT);
        relect = r;
        if (r >= NLOGB-NELECT){
            while (__hip_atomic_load(&lbar[step], __ATOMIC_ACQUIRE,
                                     __HIP_MEMORY_SCOPE_AGENT) < NLOGB) {}
        }
    }
    __syncthreads();
    if (relect >= NLOGB-NELECT){
        __threadfence();
        const int b = relect - (NLOGB-NELECT);
        const float* p0 = lp + (size_t)b*NV;
        const float* p1 = lp + (size_t)(NB+b)*NV;
        const float* p2 = lp + (size_t)(2*NB+b)*NV;
        const float* p3 = lp + (size_t)(3*NB+b)*NV;
        float* dst = out_logits + ((size_t)b*NTD + step)*NV;
        float m=-3.4e38f; int mi=NV;
        for (int v=tid; v<NV; v+=256){
            const float l = p0[v]+p1[v]+p2[v]+p3[v]+b_out[v];
            dst[v]=l;
            if (l>m){ m=l; mi=v; }
        }
        rv[tid]=m; ri[tid]=mi; __syncthreads();
        for (int s=128;s>0;s>>=1){
            if (tid<s){
                if (rv[tid+s]>rv[tid] || (rv[tid+s]==rv[tid] && ri[tid+s]<ri[tid])){
                    rv[tid]=rv[tid+s]; ri[tid]=ri[tid+s];
                }
            }
            __syncthreads();
        }
        m=rv[0]; mi=ri[0]; __syncthreads();
        float ss=0.f;
        for (int v=tid; v<NV; v+=256) ss += expf(dst[v]-m);
        rv[tid]=ss; __syncthreads();
        for (int s=128;s>0;s>>=1){ if(tid<s) rv[tid]+=rv[tid+s]; __syncthreads(); }
        if (tid==0){
            prev[b]=mi;
            out_preds[b*NTD+step]=(float)mi;
            out_ylp[b*NTD+step]=-logf(rv[0]);
        }
    }
}

// ---------------------------------------------------------------------------
extern "C" void kernel_launch(void* const* d_in, const int* in_sizes, int n_in,
                              void* d_out, int out_size, void* d_ws, size_t ws_size,
                              hipStream_t stream)
{
    const float* enc_pad   = (const float*)d_in[0];
    const int*   enc_len   = (const int*)d_in[1];
    const float* embedding = (const float*)d_in[2];
    const float* W_ih      = (const float*)d_in[3];
    const float* b_ih      = (const float*)d_in[4];
    const float* W_hh      = (const float*)d_in[5];
    const float* b_hh      = (const float*)d_in[6];
    const float* W_enc     = (const float*)d_in[7];
    const float* b_enc     = (const float*)d_in[8];
    const float* W_dec     = (const float*)d_in[9];
    const float* W_att     = (const float*)d_in[10];
    const float* conv_k    = (const float*)d_in[11];
    const float* W_g       = (const float*)d_in[12];
    const float* W_o       = (const float*)d_in[13];
    const float* b_o       = (const float*)d_in[14];
    const float* W_out     = (const float*)d_in[15];
    const float* b_out     = (const float*)d_in[16];

    float* out_logits = (float*)d_out;                        // [B,TD,V]
    float* out_ylp    = out_logits + (size_t)NB*NTD*NV;       // [B,TD]
    float* out_preds  = out_ylp + NB*NTD;                     // [B,TD]
    float* out_ws     = out_preds + NB*NTD;                   // [B,TD,T]

    float* f = (float*)d_ws;
    float* pre_enc = f;                                   // 9600*256
    float* enc_o   = pre_enc + (size_t)NB*NT*NA;          // 9600*512
    float* zbuf    = enc_o + (size_t)NB*NT*NAO;           // 32*512
    float* cA      = zbuf + NB*NH;                        // 32*512
    float* cB      = cA + NB*NH;                          // 32*512
    float* gp      = cB + NB*NH;                          // 4*32*2048
    float* cvp     = gp + 4*NB*2048;                      // 5*32*512
    float* ebuf    = cvp + 5*NB*NAO;                      // 32*300
    float* wA      = ebuf + NB*NT;                        // 32*300
    float* wB      = wA + NB*NT;                          // 32*300
    float* lp      = wB + NB*NT;                          // 4*32*10000
    int*   prev    = (int*)(lp + (size_t)4*NB*NV);        // 32
    int*   abar    = prev + NB;                           // NTD*NB
    int*   lbar    = abar + NTD*NB;                       // NTD

    k_init<<<512, 256, 0, stream>>>(enc_len, zbuf, cA, cvp, wA, prev, abar, lbar);
    k_gemm_pre<<<dim3(NA/64,  NB*NT/64), 256, 0, stream>>>(enc_pad, W_enc, b_enc, pre_enc, NA);
    k_gemm_pre<<<dim3(NAO/64, NB*NT/64), 256, 0, stream>>>(enc_pad, W_o,   b_o,   enc_o,   NAO);

    for (int s = 0; s < NTD; ++s) {
        float* cin  = (s & 1) ? cB : cA;
        float* cout = (s & 1) ? cA : cB;
        float* win  = (s & 1) ? wB : wA;
        float* wout = (s & 1) ? wA : wB;
        k_gates <<<dim3(64,4),  256, 0, stream>>>(embedding, prev, cvp, zbuf, W_ih, W_hh, gp);
        k_attn  <<<dim3(5,32),  256, 0, stream>>>(gp, b_ih, b_hh, cin, cout, zbuf,
                                                  W_dec, pre_enc, win, conv_k, W_att, W_g,
                                                  ebuf, enc_o, cvp, wout, out_ws, abar, s);
        k_logits<<<dim3(313,4), 256, 0, stream>>>(zbuf, cvp, W_out, lp, b_out, s,
                                                  out_logits, prev, out_preds, out_ylp, lbar);
    }
}